// Round 8
// baseline (36.798 us; speedup 1.0000x reference)
//
#include <hip/hip_runtime.h>

// CASSI base-mode forward on MI355X (gfx950).
// x:  (1, 31, 1024, 1024) f32, ca: (1, 1, 1024, 1024) f32
// out: (1, 1, 1024, 1054) f32
// Gather: out[m][c] = sum_l x[l][m][c-l] * ca[m][c-l].
//
// Round-8 = round-6 (best: 25.5us) minus its only scheduling waste:
// R6's 5th col-tile per row was a ghost (30/256 outputs, full latency cost,
// 20% of slots, 2.5 resident rounds). Now grid = 4x1024 = 4096 full blocks
// = exactly 2.0 balanced resident rounds at 8 blocks/CU. The 30 tail output
// columns per row fold into the bx==3 block: its staged sca window
// (cols 738..1023) already covers the tail's taps (cols 994..1023 -> sca
// indices 256..285), and those x lines were just loaded by this same block
// (L1/L2 hits). 30 threads compute one extra short output each.
// R7's 62-load/2-output pipeline is reverted (regressed: 27.8us).

constexpr int L = 31;
constexpr int M = 1024;
constexpr int N = 1024;
constexpr int NC = N + L - 1;            // 1054 output columns
constexpr int LSTRIDE = M * N;
constexpr int BLK = 256;
constexpr int HALO = L - 1;              // 30
constexpr int CA_TILE = BLK + HALO;      // 286 staged ca columns
constexpr int GX = 4;                    // full col-tiles per row (4*256 = N)
constexpr int NWG = GX * M;              // 4096 workgroups (== 0 mod 8)
constexpr int QX = NWG / 8;              // 512

__global__ __launch_bounds__(BLK, 8) void cassi_fwd_kernel(
    const float* __restrict__ x,
    const float* __restrict__ ca,
    float* __restrict__ out)
{
    __shared__ float sca[CA_TILE];

    // Bijective XCD-chunked swizzle: give each XCD a contiguous logical
    // chunk so same-row neighbor tiles (shared halo lines) share one L2.
    const int orig = blockIdx.x;
    const int wg   = (orig & 7) * QX + (orig >> 3);
    const int m    = wg >> 2;             // row
    const int bx   = wg & 3;              // col-tile within row
    const int C0   = bx * BLK;
    const int t    = threadIdx.x;

    // Stage ca[m][C0-30 .. C0+255], zero-padded outside [0,N).
    for (int i = t; i < CA_TILE; i += BLK) {
        const int col = C0 - HALO + i;
        sca[i] = ((unsigned)col < (unsigned)N) ? ca[m * N + col] : 0.0f;
    }
    __syncthreads();

    // Main output: c = C0 + t <= 1023, always valid.
    // x offsets proven in-bounds: max (l=30,m=1023,c=1023) < 31*2^20;
    // min (l>=1, c<l) >= 2^20 - 30 > 0 (garbage * 0.0 from zero pad).
    const int c = C0 + t;
    const float* xp = x + m * N + c;
    float acc = 0.0f;
#pragma unroll
    for (int l = 0; l < L; ++l) {
        acc = fmaf(xp[l * LSTRIDE - l], sca[t + HALO - l], acc);
    }
    out[m * NC + c] = acc;

    // Tail fold: bx==3 handles output cols 1024..1053 with 30 threads.
    // c2 = 1024 + t needs taps l in [t+1, 30], reading cols c2-l in
    // [994, 1023] -> sca index c2 - l - (C0 - HALO) = 286 + t - l in
    // [256, 285]: inside the staged window, no re-stage needed.
    if (bx == 3 && t < HALO) {
        const int c2 = N + t;
        float a = 0.0f;
        for (int l = t + 1; l < L; ++l) {
            a = fmaf(x[(long)l * LSTRIDE + m * N + (c2 - l)],
                     sca[CA_TILE + t - l], a);
        }
        out[m * NC + c2] = a;
    }
}

extern "C" void kernel_launch(void* const* d_in, const int* in_sizes, int n_in,
                              void* d_out, int out_size, void* d_ws, size_t ws_size,
                              hipStream_t stream)
{
    const float* x  = (const float*)d_in[0];
    const float* ca = (const float*)d_in[1];
    float* out = (float*)d_out;

    dim3 block(BLK, 1, 1);
    dim3 grid(NWG, 1, 1);                 // 4096 blocks, 1-D for the swizzle
    cassi_fwd_kernel<<<grid, block, 0, stream>>>(x, ca, out);
}

// Round 10
// 28.047 us; speedup vs baseline: 1.3120x; 1.3120x over previous
//
#include <hip/hip_runtime.h>

// CASSI base-mode forward on MI355X (gfx950).
// x:  (1, 31, 1024, 1024) f32, ca: (1, 1, 1024, 1024) f32
// out: (1, 1, 1024, 1054) f32
// Gather: out[m][c] = sum_l x[l][m][c-l] * ca[m][c-l].
//
// Round-10: single-kernel ghost-tile elimination.
//  - R9 (two kernels) tripped a harness graph-replay hazard (post-timing
//    divergence == poisoned columns; tripwire fired) -> ONE kernel only.
//  - Grid = 120 tail blocks (orig<120; cols 1024..1053, 256 outputs each,
//    direct global reads of L2-warm lines, early return) + 4096 main blocks
//    (R6's proven body, byte-identical: 31-tap unroll, 286-float zero-padded
//    sca stage, XCD-chunked swizzle, launch_bounds(256,8) -> 32 waves/CU).
//  - vs R6: no ghost 5th tile per row (was 1024 blocks x full 31-load
//    latency for 30/256 real outputs); vs R8: branch is block-uniform and
//    BEFORE the main body with disjoint paths, so the main loop's register
//    pipeline can't be poisoned by tail live ranges.

constexpr int L = 31;
constexpr int M = 1024;
constexpr int N = 1024;
constexpr int NC = N + L - 1;            // 1054 output columns
constexpr int LSTRIDE = M * N;
constexpr int BLK = 256;
constexpr int HALO = L - 1;              // 30
constexpr int CA_TILE = BLK + HALO;      // 286 staged ca columns
constexpr int GX = 4;                    // full col-tiles per row
constexpr int NWG = GX * M;              // 4096 main blocks (== 0 mod 8)
constexpr int QX = NWG / 8;              // 512
constexpr int NTAIL = (M * HALO) / BLK;  // 120 tail blocks (exact: 30720/256)

__global__ __launch_bounds__(BLK, 8) void cassi_fwd_kernel(
    const float* __restrict__ x,
    const float* __restrict__ ca,
    float* __restrict__ out)
{
    __shared__ float sca[CA_TILE];
    const int t = threadIdx.x;
    const int orig = blockIdx.x;

    if (orig < NTAIL) {
        // Tail path: output cols 1024..1053, 256 outputs per block.
        const int g = orig * BLK + t;               // 0 .. 30719
        const int m = g / HALO;
        const int c = N + (g - m * HALO);           // 1024..1053
        const int llo = c - (N - 1);                // 1..30
        float a = 0.0f;
        for (int l = llo; l < L; ++l) {
            const int col = c - l;                  // 994..1023
            a = fmaf(x[(long)l * LSTRIDE + m * N + col], ca[m * N + col], a);
        }
        out[m * NC + c] = a;
        return;
    }

    // Main path: R6's body, unchanged. Bijective XCD-chunked swizzle
    // (tail uses orig 0..119; 120 % 8 == 0 keeps the XCD phase of wg).
    const int wg = orig - NTAIL;
    const int sw = (wg & 7) * QX + (wg >> 3);
    const int m  = sw >> 2;               // row
    const int C0 = (sw & 3) * BLK;        // col-tile origin (0..768)

    // Stage ca[m][C0-30 .. C0+255], zero-padded outside [0,N).
    for (int i = t; i < CA_TILE; i += BLK) {
        const int col = C0 - HALO + i;
        sca[i] = ((unsigned)col < (unsigned)N) ? ca[m * N + col] : 0.0f;
    }
    __syncthreads();

    // c = C0 + t <= 1023: always a real output. x offsets in-bounds:
    // max (l=30,m=1023,c=1023) < 31*2^20; min (l>=1,c<l) >= 2^20-30 > 0
    // (in-allocation garbage * 0.0 from the zero pad).
    const int c = C0 + t;
    const float* xp = x + m * N + c;
    float acc = 0.0f;
#pragma unroll
    for (int l = 0; l < L; ++l) {
        acc = fmaf(xp[l * LSTRIDE - l], sca[t + HALO - l], acc);
    }
    out[m * NC + c] = acc;
}

extern "C" void kernel_launch(void* const* d_in, const int* in_sizes, int n_in,
                              void* d_out, int out_size, void* d_ws, size_t ws_size,
                              hipStream_t stream)
{
    const float* x  = (const float*)d_in[0];
    const float* ca = (const float*)d_in[1];
    float* out = (float*)d_out;

    dim3 block(BLK, 1, 1);
    dim3 grid(NTAIL + NWG, 1, 1);         // 4216 blocks; cheap tails first
    cassi_fwd_kernel<<<grid, block, 0, stream>>>(x, ca, out);
}

// Round 11
// 25.395 us; speedup vs baseline: 1.4490x; 1.1044x over previous
//
#include <hip/hip_runtime.h>

// CASSI base-mode forward on MI355X (gfx950).
// x:  (1, 31, 1024, 1024) f32, ca: (1, 1, 1024, 1024) f32
// out: (1, 1, 1024, 1054) f32
// Gather: out[m][c] = sum_l x[l][m][c-l] * ca[m][c-l]; each x element is
// touched exactly once (tap l selects slice l) -> compulsory ~138 MB.
//
// FINAL (= round-6, best measured: 25.47us, ~5.6 TB/s effective ≈ 90% of
// the m13-measured 6.29 TB/s memory-path ceiling):
//  (1) 286-float zero-padded ca window staged in LDS (kills the 31x ca
//      re-read that round-1 showed was evicted from L2 by the x stream).
//  (2) __launch_bounds__(256,8): 32 waves/CU -> 2x load concurrency (+13%).
//  (3) bijective XCD-chunked block swizzle: same-row neighbor blocks share
//      ca halo + straddled 64B lines on one XCD's L2.
//  (4) divergence-free 31-tap fully-unrolled loop (clamp, predicated store).
// Post-mortems: R7 (62-load unroll), R8 (tail fold branch), R9 (two-kernel
// graph hazard), R10 (branchy tail path) ALL regressed vs this structure —
// the compiler's 31-deep load pipeline here is the local optimum; added
// control flow costs more than the ~20% ghost-tile slot waste it recovers.

constexpr int L = 31;
constexpr int M = 1024;
constexpr int N = 1024;
constexpr int NC = N + L - 1;            // 1054 output columns
constexpr int LSTRIDE = M * N;           // elements between successive l-slices
constexpr int BLK = 256;
constexpr int HALO = L - 1;              // 30
constexpr int CA_TILE = BLK + HALO;      // 286 staged ca columns
constexpr int GX = (NC + BLK - 1) / BLK; // 5 column-blocks per row
constexpr int NWG = GX * M;              // 5120 workgroups (== 0 mod 8)
constexpr int NXCD = 8;
constexpr int QX = NWG / NXCD;           // 640

__global__ __launch_bounds__(BLK, 8) void cassi_fwd_kernel(
    const float* __restrict__ x,
    const float* __restrict__ ca,
    float* __restrict__ out)
{
    __shared__ float sca[CA_TILE];

    // XCD-chunked swizzle (bijective since NWG % 8 == 0).
    const int orig = blockIdx.x;
    const int wg   = (orig & 7) * QX + (orig >> 3);
    const int m    = wg / GX;
    const int bx   = wg - m * GX;
    const int C0   = bx * BLK;
    const int tid  = threadIdx.x;

    // Stage ca[m][C0-30 .. C0+255] into LDS, zero-padded outside [0,N).
    for (int i = tid; i < CA_TILE; i += BLK) {
        const int col = C0 - HALO + i;
        sca[i] = ((unsigned)col < (unsigned)N) ? ca[m * N + col] : 0.0f;
    }
    __syncthreads();

    const int c  = C0 + tid;
    const int cw = (c < NC) ? tid : (NC - 1 - C0);   // clamped in-block col
    const float* xp = x + m * N + C0 + cw;

    // All 31 tap offsets proven in-bounds: max index (l=30,m=1023,c=1053)
    // = 31*2^20 - 1; min (l>=1, c<l) >= 2^20 - 30 > 0 (pad value * 0.0).
    float acc = 0.0f;
#pragma unroll
    for (int l = 0; l < L; ++l) {
        acc = fmaf(xp[l * LSTRIDE - l], sca[cw + HALO - l], acc);
    }

    if (c < NC) out[m * NC + c] = acc;
}

extern "C" void kernel_launch(void* const* d_in, const int* in_sizes, int n_in,
                              void* d_out, int out_size, void* d_ws, size_t ws_size,
                              hipStream_t stream)
{
    const float* x  = (const float*)d_in[0];
    const float* ca = (const float*)d_in[1];
    float* out = (float*)d_out;

    dim3 block(BLK, 1, 1);
    dim3 grid(NWG, 1, 1);                 // 5120 blocks, 1-D for the swizzle
    cassi_fwd_kernel<<<grid, block, 0, stream>>>(x, ca, out);
}